// Round 10
// baseline (31966.888 us; speedup 1.0000x reference)
//
#include <hip/hip_runtime.h>
#include <cstdint>
#include <math.h>

#define U 896
#define HU 448
#define TU 2688
#define TT 512
#define MM 80
#define CC 256
#define NTH 512
#define NBLK 72

// ---------------- Threefry-2x32 (JAX partitionable) ----------------
__device__ __forceinline__ uint32_t rotl32(uint32_t v, int r){ return (v<<r)|(v>>(32-r)); }

__device__ void threefry(uint32_t k0, uint32_t k1, uint32_t x0, uint32_t x1,
                         uint32_t* o0, uint32_t* o1){
  uint32_t k2 = k0 ^ k1 ^ 0x1BD11BDAu;
  x0 += k0; x1 += k1;
  x0+=x1; x1=rotl32(x1,13); x1^=x0;
  x0+=x1; x1=rotl32(x1,15); x1^=x0;
  x0+=x1; x1=rotl32(x1,26); x1^=x0;
  x0+=x1; x1=rotl32(x1, 6); x1^=x0;
  x0+=k1; x1+=k2+1u;
  x0+=x1; x1=rotl32(x1,17); x1^=x0;
  x0+=x1; x1=rotl32(x1,29); x1^=x0;
  x0+=x1; x1=rotl32(x1,16); x1^=x0;
  x0+=x1; x1=rotl32(x1,24); x1^=x0;
  x0+=k2; x1+=k0+2u;
  x0+=x1; x1=rotl32(x1,13); x1^=x0;
  x0+=x1; x1=rotl32(x1,15); x1^=x0;
  x0+=x1; x1=rotl32(x1,26); x1^=x0;
  x0+=x1; x1=rotl32(x1, 6); x1^=x0;
  x0+=k0; x1+=k1+3u;
  x0+=x1; x1=rotl32(x1,17); x1^=x0;
  x0+=x1; x1=rotl32(x1,29); x1^=x0;
  x0+=x1; x1=rotl32(x1,16); x1^=x0;
  x0+=x1; x1=rotl32(x1,24); x1^=x0;
  x0+=k1; x1+=k2+4u;
  x0+=x1; x1=rotl32(x1,13); x1^=x0;
  x0+=x1; x1=rotl32(x1,15); x1^=x0;
  x0+=x1; x1=rotl32(x1,26); x1^=x0;
  x0+=x1; x1=rotl32(x1, 6); x1^=x0;
  x0+=k2; x1+=k0+5u;
  *o0 = x0; *o1 = x1;
}

__device__ float gumbel_from(uint32_t ka, uint32_t kb, uint32_t e){
  uint32_t o0, o1;
  threefry(ka, kb, 0u, e, &o0, &o1);
  uint32_t bits = o0 ^ o1;
  uint32_t m = bits >> 9;
  float u = (m == 0u) ? 1.17549435e-38f
                      : (__uint_as_float(m | 0x3f800000u) - 1.0f);
  float l1 = (float)log((double)u);
  float l2 = (float)log((double)(-l1));
  return -l2;
}

__device__ __forceinline__ float sig_f(float x){
  return (float)(0.5 + 0.5*tanh(0.5*(double)x));
}
__device__ __forceinline__ float tanh_f(float x){ return (float)tanh((double)x); }

// ---------------- coherent (agent-scope) access ----------------
__device__ __forceinline__ float2 gldf2(const float* p){
  unsigned long long v = __hip_atomic_load((const unsigned long long*)p,
                                           __ATOMIC_RELAXED, __HIP_MEMORY_SCOPE_AGENT);
  union { unsigned long long u; float2 f; } cv; cv.u = v; return cv.f;
}
__device__ __forceinline__ void gstf2(float* p, float2 f){
  union { float2 f; unsigned long long u; } cv; cv.f = f;
  __hip_atomic_store((unsigned long long*)p, cv.u,
                     __ATOMIC_RELAXED, __HIP_MEMORY_SCOPE_AGENT);
}

// ---------------- tagged-value transport ----------------
__device__ __forceinline__ float2 tg_try(const float* b2, int idx){
  return gldf2(b2 + ((size_t)idx<<1));
}
__device__ __forceinline__ float tg_resolve(const float* b2, int idx, uint32_t tag, float2 v){
  int it = 0;
  while (__float_as_uint(v.y) != tag){
    v = gldf2(b2 + ((size_t)idx<<1));
    if (++it > (1<<24)) break;
  }
  return v.x;
}
__device__ __forceinline__ float tg_poll(const float* b2, int idx, uint32_t tag){
  return tg_resolve(b2, idx, tag, tg_try(b2, idx));
}
__device__ __forceinline__ void tg_put(float* b2, int idx, float v, uint32_t tag){
  gstf2(b2 + ((size_t)idx<<1), make_float2(v, __uint_as_float(tag)));
}

__device__ __forceinline__ void fma4(float4& a, const float4& w, float h){
  a.x += w.x*h; a.y += w.y*h; a.z += w.z*h; a.w += w.w*h;
}

// butterfly-sum 8 float4 accumulators over lane bits 3..5
__device__ __forceinline__ void bf8(float4* a){
  #pragma unroll
  for (int d=8; d<64; d<<=1){
    #pragma unroll
    for (int b=0;b<8;++b){
      a[b].x += __shfl_xor(a[b].x, d);
      a[b].y += __shfl_xor(a[b].y, d);
      a[b].z += __shfl_xor(a[b].z, d);
      a[b].w += __shfl_xor(a[b].w, d);
    }
  }
}

// tournament over 256 classes, 4/lane in one 64-lane wave (r8-proven)
__device__ __forceinline__ int sample256(float l0, float l1, float l2, float l3,
                                         const float g[4], int gl){
  float m = fmaxf(fmaxf(l0,l1), fmaxf(l2,l3));
  #pragma unroll
  for (int d=1; d<64; d<<=1) m = fmaxf(m, __shfl_xor(m, d));
  const float e0 = (float)exp((double)(l0-m));
  const float e1 = (float)exp((double)(l1-m));
  const float e2 = (float)exp((double)(l2-m));
  const float e3 = (float)exp((double)(l3-m));
  float ss = ((e0+e1)+(e2+e3));
  #pragma unroll
  for (int d=1; d<64; d<<=1) ss += __shfl_xor(ss, d);
  const float v0 = e0/ss + g[0], v1 = e1/ss + g[1];
  const float v2 = e2/ss + g[2], v3 = e3/ss + g[3];
  float v = v0; int bi = 4*gl;
  if (v1 > v){ v = v1; bi = 4*gl+1; }
  float vB = v2; int biB = 4*gl+2;
  if (v3 > vB){ vB = v3; biB = 4*gl+3; }
  if (vB > v || (vB == v && biB < bi)){ v = vB; bi = biB; }
  #pragma unroll
  for (int d=1; d<64; d<<=1){
    const float ov = __shfl_xor(v, d);
    const int   oi = __shfl_xor(bi, d);
    if (ov > v || (ov == v && oi < bi)){ v = ov; bi = oi; }
  }
  return bi;
}

// ---------------- K0: per-step keys ----------------
__global__ __launch_bounds__(256) void k_keys(uint32_t* __restrict__ kc, uint32_t* __restrict__ kf){
  int t = blockIdx.x*256 + threadIdx.x;
  if (t >= TT) return;
  uint32_t ka, kb;
  threefry(0u, 42u, 0u, (uint32_t)t, &ka, &kb);
  uint32_t c0,c1,f0,f1;
  threefry(ka, kb, 0u, 0u, &c0, &c1);
  threefry(ka, kb, 0u, 1u, &f0, &f1);
  kc[2*t] = c0; kc[2*t+1] = c1;
  kf[2*t] = f0; kf[2*t+1] = f1;
}

// ws offsets (tagged buffers hold 2 floats per element)
#define O_KC    0
#define O_KF    4096
#define O_NCV   8192
#define O_NCI   8256
#define O_FV    8320
#define O_PRE   8448
#define O_IHB   180480
#define O_HGL   237824
#define O_H0C   295168
#define O_Y1C   323840
#define O_Y1F   352512
#define O_H1H   381184
#define WS_ZERO 409856

// ---------------- persistent kernel ----------------
__global__ __launch_bounds__(NTH, 2) void wavernn_persist(
    const float* __restrict__ mels, const float* __restrict__ Wk,
    const float* __restrict__ Wr,  const float* __restrict__ bias,
    const float* __restrict__ W1c, const float* __restrict__ b1c,
    const float* __restrict__ W2c, const float* __restrict__ b2c,
    const float* __restrict__ W1f, const float* __restrict__ b1f,
    const float* __restrict__ W2f, const float* __restrict__ b2f,
    float* __restrict__ out, char* __restrict__ ws)
{
  const uint32_t* kc = (const uint32_t*)(ws + O_KC);
  const uint32_t* kf = (const uint32_t*)(ws + O_KF);
  float* ncv2 = (float*)(ws + O_NCV);
  float* nci2 = (float*)(ws + O_NCI);
  float* fv2  = (float*)(ws + O_FV);
  float* pre2 = (float*)(ws + O_PRE);   // [8][2688] tagged
  float* ihb2 = (float*)(ws + O_IHB);   // [8][896]  tagged
  float* hgl2 = (float*)(ws + O_HGL);   // [8][896]  tagged
  float* h0c2 = (float*)(ws + O_H0C);   // [8][448]  tagged
  float* y1c2 = (float*)(ws + O_Y1C);   // [8][448]  tagged
  float* y1f2 = (float*)(ws + O_Y1F);   // [8][448]  tagged
  float* h1h2 = (float*)(ws + O_H1H);   // [8][448]  tagged

  const int bk = blockIdx.x, tid = threadIdx.x;

  if (bk < 28){
    // ================= GEMM + coarse-gates epilogue =================
    __shared__ __align__(16) float hlf[8*1024];
    __shared__ __align__(16) float wredf[8*288];
    __shared__ __align__(16) float gbuf[1024];
    __shared__ float fvSh[8];
    const int ks = tid >> 3, k0 = ks*14;
    const int lane = tid & 63, wv = tid >> 6;
    const int U0 = bk*32;
    const int cb0 = U0 + (tid & 7)*4;
    const int xk = 896 + ks*2;
    const int r0 = ((xk   < 978) ? xk   : 978) - 896;
    const int r1 = ((xk+1 < 978) ? xk+1 : 978) - 896;

    for (int t=0; t<TT; ++t){
      const uint32_t tgIn = (uint32_t)t, tgOut = (uint32_t)(t+1);
      __syncthreads();
      // batched tagged staging of h (14/thread)
      {
        float2 vh[14];
        #pragma unroll
        for (int q=0;q<14;++q) vh[q] = tg_try(hgl2, tid + q*NTH);
        #pragma unroll
        for (int q=0;q<14;++q){
          const int i = tid + q*NTH, b = i/896, k = i - b*896;
          hlf[b*1024 + k] = tg_resolve(hgl2, i, tgIn, vh[q]);
        }
      }
      // x region (mel(t), cv = ncv(t-1), pad)
      #pragma unroll
      for (int q=0;q<2;++q){
        const int i = tid + q*NTH, b = i>>7, k2 = i&127;
        float v = 0.f;
        if (k2 < 80) v = mels[((size_t)b*TT + t)*MM + k2];
        else if (k2 == 80) v = tg_poll(ncv2, b, tgIn);
        hlf[b*1024 + 896 + k2] = v;
      }
      __syncthreads();

      for (int g=0; g<3; ++g){
        const int cbg = g*896 + cb0;
        float4 aW[8], aX[8];
        #pragma unroll
        for (int b=0;b<8;++b){ aW[b]=make_float4(0,0,0,0); aX[b]=make_float4(0,0,0,0); }
        #pragma unroll 2
        for (int jj=0;jj<14;++jj){
          const float4 w = *(const float4*)(Wr + (size_t)(k0+jj)*TU + cbg);
          #pragma unroll
          for (int b=0;b<8;++b) fma4(aW[b], w, hlf[b*1024 + k0 + jj]);
        }
        {
          const float4 w0 = *(const float4*)(Wk + (size_t)r0*TU + cbg);
          const float4 w1 = *(const float4*)(Wk + (size_t)r1*TU + cbg);
          #pragma unroll
          for (int b=0;b<8;++b){
            fma4(aX[b], w0, hlf[b*1024 + 896 + ks*2]);
            fma4(aX[b], w1, hlf[b*1024 + 897 + ks*2]);
          }
        }
        if (g < 2){
          #pragma unroll
          for (int b=0;b<8;++b){
            aW[b].x += aX[b].x; aW[b].y += aX[b].y;
            aW[b].z += aX[b].z; aW[b].w += aX[b].w;
          }
          bf8(aW);
          if (lane < 8){
            float* dst = wredf + wv*288 + lane*36;
            #pragma unroll
            for (int b=0;b<8;++b) *(float4*)(dst + b*4) = aW[b];
          }
          __syncthreads();
          if (tid < 128){
            const int rb = tid>>4, rq = tid&15;
            float s0 = 0.f, s1 = 0.f;
            #pragma unroll
            for (int w=0; w<8; ++w){
              const float* wp = wredf + w*288 + (rq>>1)*36 + rb*4 + ((2*rq)&3);
              s0 += wp[0]; s1 += wp[1];
            }
            const int col0 = g*896 + U0 + 2*rq;
            const float v0 = s0 + bias[col0]   + bias[TU + col0];
            const float v1 = s1 + bias[col0+1] + bias[TU + col0+1];
            tg_put(pre2, rb*TU + col0,     v0, tgOut);
            tg_put(pre2, rb*TU + col0 + 1, v1, tgOut);
            gbuf[(rb*32 + 2*rq)*4 + g]     = v0;
            gbuf[(rb*32 + 2*rq + 1)*4 + g] = v1;
          }
          __syncthreads();
        } else {
          bf8(aW);
          if (lane < 8){
            float* dst = wredf + wv*288 + lane*36;
            #pragma unroll
            for (int b=0;b<8;++b) *(float4*)(dst + b*4) = aW[b];
          }
          __syncthreads();
          if (tid < 128){
            const int rb = tid>>4, rq = tid&15;
            float s0 = 0.f, s1 = 0.f;
            #pragma unroll
            for (int w=0; w<8; ++w){
              const float* wp = wredf + w*288 + (rq>>1)*36 + rb*4 + ((2*rq)&3);
              s0 += wp[0]; s1 += wp[1];
            }
            const int u0 = U0 + 2*rq;
            const float v0 = s0 + bias[TU + 1792 + u0];
            const float v1 = s1 + bias[TU + 1792 + u0 + 1];
            tg_put(ihb2, rb*896 + u0,     v0, tgOut);
            tg_put(ihb2, rb*896 + u0 + 1, v1, tgOut);
            gbuf[(rb*32 + 2*rq)*4 + 3]     = v0;
            gbuf[(rb*32 + 2*rq + 1)*4 + 3] = v1;
          }
          __syncthreads();
          bf8(aX);
          if (lane < 8){
            float* dst = wredf + wv*288 + lane*36;
            #pragma unroll
            for (int b=0;b<8;++b) *(float4*)(dst + b*4) = aX[b];
          }
          __syncthreads();
          if (tid < 128){
            const int rb = tid>>4, rq = tid&15;
            float s0 = 0.f, s1 = 0.f;
            #pragma unroll
            for (int w=0; w<8; ++w){
              const float* wp = wredf + w*288 + (rq>>1)*36 + rb*4 + ((2*rq)&3);
              s0 += wp[0]; s1 += wp[1];
            }
            const int u0 = U0 + 2*rq;
            const float v0 = s0 + bias[1792 + u0];
            const float v1 = s1 + bias[1792 + u0 + 1];
            tg_put(pre2, rb*TU + 1792 + u0,     v0, tgOut);
            tg_put(pre2, rb*TU + 1792 + u0 + 1, v1, tgOut);
            gbuf[(rb*32 + 2*rq)*4 + 2]     = v0;
            gbuf[(rb*32 + 2*rq + 1)*4 + 2] = v1;
          }
          __syncthreads();
        }
      }

      if (bk < 14){
        // coarse gates epilogue (needs fv(t-1) tagged t)
        if (tid < 8) fvSh[tid] = tg_poll(fv2, tid, tgIn);
        __syncthreads();
        if (tid < 128){
          const int b = tid>>4, q = tid&15;
          const int u0 = U0 + 2*q;
          const float fv = fvSh[b];
          const float2 wz = *(const float2*)(Wk + (size_t)81*TU + u0);
          const float2 wr = *(const float2*)(Wk + (size_t)81*TU + 896 + u0);
          const float2 wx = *(const float2*)(Wk + (size_t)81*TU + 1792 + u0);
          const float* g0 = gbuf + (b*32 + 2*q)*4;
          const float* g1 = g0 + 4;
          const float az0 = g0[0] + fv*wz.x, az1 = g1[0] + fv*wz.y;
          const float ar0 = g0[1] + fv*wr.x, ar1 = g1[1] + fv*wr.y;
          const float ax0 = g0[2] + fv*wx.x, ax1 = g1[2] + fv*wx.y;
          const float z0 = sig_f(az0), z1 = sig_f(az1);
          const float r0g = sig_f(ar0), r1g = sig_f(ar1);
          const float hh0 = tanh_f(ax0 + r0g*g0[3]);
          const float hh1 = tanh_f(ax1 + r1g*g1[3]);
          tg_put(h0c2, b*HU + u0,     z0*hlf[b*1024 + u0]     + (1.0f - z0)*hh0, tgOut);
          tg_put(h0c2, b*HU + u0 + 1, z1*hlf[b*1024 + u0 + 1] + (1.0f - z1)*hh1, tgOut);
        }
      }
    }
  } else if (bk < 56){
    // ================= head slice block j: phase C then phase F =================
    const int j = bk - 28;
    __shared__ __align__(16) float hstg[3584];
    __shared__ __align__(16) float red1[512];
    const int outp = tid & 127, ks4 = tid >> 7;
    const int ob = outp >> 4, oc = outp & 15;
    const int i0 = ks4*112;

    for (int t=0; t<TT; ++t){
      const uint32_t tg = (uint32_t)(t+1);
      // ---------- phase C ----------
      __syncthreads();
      {
        float2 vh[7];
        #pragma unroll
        for (int q=0;q<7;++q) vh[q] = tg_try(h0c2, tid + q*NTH);
        #pragma unroll
        for (int q=0;q<7;++q) hstg[tid + q*NTH] = tg_resolve(h0c2, tid + q*NTH, tg, vh[q]);
      }
      __syncthreads();
      {
        float s = 0.f;
        const float* hb = hstg + ob*HU;
        const float* wb = W1c + (size_t)i0*HU + j*16 + oc;
        #pragma unroll 4
        for (int i=0;i<112;++i) s += hb[i0+i]*wb[(size_t)i*HU];
        red1[outp*4 + ks4] = s;
      }
      __syncthreads();
      if (tid < 128){
        const float v = (red1[tid*4+0]+red1[tid*4+1])+(red1[tid*4+2]+red1[tid*4+3]);
        const float y = fmaxf(v + b1c[j*16 + (tid&15)], 0.0f);
        tg_put(y1c2, (tid>>4)*HU + j*16 + (tid&15), y, tg);
      }
      // ---------- phase F ----------
      __syncthreads();
      {
        float2 vh[7];
        #pragma unroll
        for (int q=0;q<7;++q) vh[q] = tg_try(h1h2, tid + q*NTH);
        #pragma unroll
        for (int q=0;q<7;++q) hstg[tid + q*NTH] = tg_resolve(h1h2, tid + q*NTH, tg, vh[q]);
      }
      __syncthreads();
      {
        float s = 0.f;
        const float* hb = hstg + ob*HU;
        const float* wb = W1f + (size_t)i0*HU + j*16 + oc;
        #pragma unroll 4
        for (int i=0;i<112;++i) s += hb[i0+i]*wb[(size_t)i*HU];
        red1[outp*4 + ks4] = s;
      }
      __syncthreads();
      if (tid < 128){
        const float v = (red1[tid*4+0]+red1[tid*4+1])+(red1[tid*4+2]+red1[tid*4+3]);
        const float y = fmaxf(v + b1f[j*16 + (tid&15)], 0.0f);
        tg_put(y1f2, (tid>>4)*HU + j*16 + (tid&15), y, tg);
      }
    }
  } else if (bk < 64){
    // ================= coarse sampler + fine gates (b = bk-56) =================
    const int b = bk - 56;
    __shared__ __align__(16) float y1L[448];
    __shared__ __align__(16) float lgP[512];
    __shared__ __align__(16) float lg[256];
    __shared__ __align__(16) float hstate[896];
    __shared__ float fvSh;
    __shared__ int ncSh;

    for (int i=tid;i<896;i+=NTH) hstate[i] = 0.f;
    __syncthreads();

    for (int t=0; t<TT; ++t){
      const uint32_t tgIn = (uint32_t)t, tg = (uint32_t)(t+1);
      float gc[4];
      if (tid < 64){
        const uint32_t ca = kc[2*t], cb2 = kc[2*t+1];
        #pragma unroll
        for (int i=0;i<4;++i)
          gc[i] = gumbel_from(ca, cb2, (uint32_t)(b*CC + 4*tid + i));
      }
      __syncthreads();
      if (tid < 448) y1L[tid] = tg_poll(y1c2, b*HU + tid, tg);
      if (tid == 448) fvSh = tg_poll(fv2, b, tgIn);
      __syncthreads();
      // full coarse logits (2-way k-split)
      {
        const int col = tid & 255, half = tid >> 8;
        const int base = half*224;
        float s = 0.f;
        #pragma unroll 4
        for (int i=0;i<224;++i) s += y1L[base+i]*W2c[(size_t)(base+i)*CC + col];
        lgP[tid] = s;
      }
      __syncthreads();
      if (tid < 256) lg[tid] = (lgP[tid] + lgP[tid+256]) + b2c[tid];
      __syncthreads();
      if (tid < 64){
        const int nc = sample256(lg[4*tid], lg[4*tid+1], lg[4*tid+2], lg[4*tid+3], gc, tid);
        if (tid == 0){
          ncSh = nc;
          tg_put(ncv2, b, (float)nc/255.0f*2.0f - 1.0f, tg);
          tg_put(nci2, b, (float)nc, tg);
        }
      }
      __syncthreads();
      const float ncv = (float)ncSh/255.0f*2.0f - 1.0f;
      const float fv = fvSh;
      // fine gates: u = tid and u = tid+512 (batched tagged reads)
      {
        const int u = tid;
        float2 a0 = tg_try(pre2, b*TU + u);
        float2 a1 = tg_try(pre2, b*TU + 896 + u);
        float2 a2 = tg_try(pre2, b*TU + 1792 + u);
        float2 a3 = tg_try(ihb2, b*896 + u);
        const float az = tg_resolve(pre2, b*TU + u, tg, a0)        + fv*Wk[(size_t)81*TU + u]        + ncv*Wk[(size_t)82*TU + u];
        const float ar = tg_resolve(pre2, b*TU + 896 + u, tg, a1)  + fv*Wk[(size_t)81*TU + 896 + u]  + ncv*Wk[(size_t)82*TU + 896 + u];
        const float ax = tg_resolve(pre2, b*TU + 1792 + u, tg, a2) + fv*Wk[(size_t)81*TU + 1792 + u] + ncv*Wk[(size_t)82*TU + 1792 + u];
        const float ih = tg_resolve(ihb2, b*896 + u, tg, a3);
        const float z = sig_f(az), r = sig_f(ar);
        const float hh = tanh_f(ax + r*ih);
        const float hn = z*hstate[u] + (1.0f - z)*hh;
        hstate[u] = hn;
        tg_put(hgl2, b*896 + u, hn, tg);
        if (u >= HU) tg_put(h1h2, b*HU + (u - HU), hn, tg);
      }
      if (tid < 384){
        const int u = tid + 512;
        float2 a0 = tg_try(pre2, b*TU + u);
        float2 a1 = tg_try(pre2, b*TU + 896 + u);
        float2 a2 = tg_try(pre2, b*TU + 1792 + u);
        float2 a3 = tg_try(ihb2, b*896 + u);
        const float az = tg_resolve(pre2, b*TU + u, tg, a0)        + fv*Wk[(size_t)81*TU + u]        + ncv*Wk[(size_t)82*TU + u];
        const float ar = tg_resolve(pre2, b*TU + 896 + u, tg, a1)  + fv*Wk[(size_t)81*TU + 896 + u]  + ncv*Wk[(size_t)82*TU + 896 + u];
        const float ax = tg_resolve(pre2, b*TU + 1792 + u, tg, a2) + fv*Wk[(size_t)81*TU + 1792 + u] + ncv*Wk[(size_t)82*TU + 1792 + u];
        const float ih = tg_resolve(ihb2, b*896 + u, tg, a3);
        const float z = sig_f(az), r = sig_f(ar);
        const float hh = tanh_f(ax + r*ih);
        const float hn = z*hstate[u] + (1.0f - z)*hh;
        hstate[u] = hn;
        tg_put(hgl2, b*896 + u, hn, tg);
        tg_put(h1h2, b*HU + (u - HU), hn, tg);
      }
    }
  } else {
    // ================= fine sampler (b = bk-64) =================
    const int b = bk - 64;
    __shared__ __align__(16) float y1L[448];
    __shared__ __align__(16) float lgP[512];
    __shared__ __align__(16) float lg[256];
    for (int t=0; t<TT; ++t){
      const uint32_t tg = (uint32_t)(t+1);
      float gf[4];
      if (tid < 64){
        const uint32_t fa = kf[2*t], fb2 = kf[2*t+1];
        #pragma unroll
        for (int i=0;i<4;++i)
          gf[i] = gumbel_from(fa, fb2, (uint32_t)(b*CC + 4*tid + i));
      }
      __syncthreads();
      if (tid < 448) y1L[tid] = tg_poll(y1f2, b*HU + tid, tg);
      __syncthreads();
      {
        const int col = tid & 255, half = tid >> 8;
        const int base = half*224;
        float s = 0.f;
        #pragma unroll 4
        for (int i=0;i<224;++i) s += y1L[base+i]*W2f[(size_t)(base+i)*CC + col];
        lgP[tid] = s;
      }
      __syncthreads();
      if (tid < 256) lg[tid] = (lgP[tid] + lgP[tid+256]) + b2f[tid];
      __syncthreads();
      if (tid < 64){
        const int nf = sample256(lg[4*tid], lg[4*tid+1], lg[4*tid+2], lg[4*tid+3], gf, tid);
        if (tid == 0){
          tg_put(fv2, b, (float)nf/255.0f*2.0f - 1.0f, tg);
          const float ncf = tg_poll(nci2, b, tg);
          out[(size_t)b*TT + t] = (ncf*256.0f + (float)nf)/32767.5f - 1.0f;
        }
      }
      __syncthreads();
    }
  }
}

extern "C" void kernel_launch(void* const* d_in, const int* in_sizes, int n_in,
                              void* d_out, int out_size, void* d_ws, size_t ws_size,
                              hipStream_t stream) {
  const float* mels = (const float*)d_in[0];
  const float* Wk   = (const float*)d_in[1];
  const float* Wr   = (const float*)d_in[2];
  const float* bias = (const float*)d_in[3];
  const float* W1c  = (const float*)d_in[4];
  const float* b1c  = (const float*)d_in[5];
  const float* W2c  = (const float*)d_in[6];
  const float* b2c  = (const float*)d_in[7];
  const float* W1f  = (const float*)d_in[8];
  const float* b1f  = (const float*)d_in[9];
  const float* W2f  = (const float*)d_in[10];
  const float* b2f  = (const float*)d_in[11];
  float* out = (float*)d_out;
  char* wsb = (char*)d_ws;

  uint32_t* kc = (uint32_t*)(wsb + O_KC);
  uint32_t* kf = (uint32_t*)(wsb + O_KF);

  hipMemsetAsync(d_ws, 0, WS_ZERO, stream);
  k_keys<<<2,256,0,stream>>>(kc, kf);

  void* args[] = { (void*)&mels, (void*)&Wk, (void*)&Wr, (void*)&bias,
                   (void*)&W1c, (void*)&b1c, (void*)&W2c, (void*)&b2c,
                   (void*)&W1f, (void*)&b1f, (void*)&W2f, (void*)&b2f,
                   (void*)&out, (void*)&wsb };
  hipLaunchCooperativeKernel((const void*)wavernn_persist, dim3(NBLK), dim3(NTH),
                             args, 0, stream);
}

// Round 11
// 17672.241 us; speedup vs baseline: 1.8089x; 1.8089x over previous
//
#include <hip/hip_runtime.h>
#include <cstdint>
#include <math.h>

#define U 896
#define HU 448
#define TU 2688
#define TT 512
#define MM 80
#define CC 256
#define NTH 512
#define NBLK 72

// ---------------- Threefry-2x32 (JAX partitionable) ----------------
__device__ __forceinline__ uint32_t rotl32(uint32_t v, int r){ return (v<<r)|(v>>(32-r)); }

__device__ void threefry(uint32_t k0, uint32_t k1, uint32_t x0, uint32_t x1,
                         uint32_t* o0, uint32_t* o1){
  uint32_t k2 = k0 ^ k1 ^ 0x1BD11BDAu;
  x0 += k0; x1 += k1;
  x0+=x1; x1=rotl32(x1,13); x1^=x0;
  x0+=x1; x1=rotl32(x1,15); x1^=x0;
  x0+=x1; x1=rotl32(x1,26); x1^=x0;
  x0+=x1; x1=rotl32(x1, 6); x1^=x0;
  x0+=k1; x1+=k2+1u;
  x0+=x1; x1=rotl32(x1,17); x1^=x0;
  x0+=x1; x1=rotl32(x1,29); x1^=x0;
  x0+=x1; x1=rotl32(x1,16); x1^=x0;
  x0+=x1; x1=rotl32(x1,24); x1^=x0;
  x0+=k2; x1+=k0+2u;
  x0+=x1; x1=rotl32(x1,13); x1^=x0;
  x0+=x1; x1=rotl32(x1,15); x1^=x0;
  x0+=x1; x1=rotl32(x1,26); x1^=x0;
  x0+=x1; x1=rotl32(x1, 6); x1^=x0;
  x0+=k0; x1+=k1+3u;
  x0+=x1; x1=rotl32(x1,17); x1^=x0;
  x0+=x1; x1=rotl32(x1,29); x1^=x0;
  x0+=x1; x1=rotl32(x1,16); x1^=x0;
  x0+=x1; x1=rotl32(x1,24); x1^=x0;
  x0+=k1; x1+=k2+4u;
  x0+=x1; x1=rotl32(x1,13); x1^=x0;
  x0+=x1; x1=rotl32(x1,15); x1^=x0;
  x0+=x1; x1=rotl32(x1,26); x1^=x0;
  x0+=x1; x1=rotl32(x1, 6); x1^=x0;
  x0+=k2; x1+=k0+5u;
  *o0 = x0; *o1 = x1;
}

__device__ float gumbel_from(uint32_t ka, uint32_t kb, uint32_t e){
  uint32_t o0, o1;
  threefry(ka, kb, 0u, e, &o0, &o1);
  uint32_t bits = o0 ^ o1;
  uint32_t m = bits >> 9;
  float u = (m == 0u) ? 1.17549435e-38f
                      : (__uint_as_float(m | 0x3f800000u) - 1.0f);
  float l1 = (float)log((double)u);
  float l2 = (float)log((double)(-l1));
  return -l2;
}

__device__ __forceinline__ float sig_f(float x){
  return (float)(0.5 + 0.5*tanh(0.5*(double)x));
}
__device__ __forceinline__ float tanh_f(float x){ return (float)tanh((double)x); }

// ---------------- coherent (agent-scope) access ----------------
__device__ __forceinline__ float gldf(const float* p){
  return __hip_atomic_load(p, __ATOMIC_RELAXED, __HIP_MEMORY_SCOPE_AGENT);
}
__device__ __forceinline__ void gstf(float* p, float v){
  __hip_atomic_store(p, v, __ATOMIC_RELAXED, __HIP_MEMORY_SCOPE_AGENT);
}
__device__ __forceinline__ int gldi(const int* p){
  return __hip_atomic_load(p, __ATOMIC_RELAXED, __HIP_MEMORY_SCOPE_AGENT);
}
__device__ __forceinline__ void gsti(int* p, int v){
  __hip_atomic_store(p, v, __ATOMIC_RELAXED, __HIP_MEMORY_SCOPE_AGENT);
}
__device__ __forceinline__ float2 gldf2(const float* p){
  unsigned long long v = __hip_atomic_load((const unsigned long long*)p,
                                           __ATOMIC_RELAXED, __HIP_MEMORY_SCOPE_AGENT);
  union { unsigned long long u; float2 f; } cv; cv.u = v; return cv.f;
}
__device__ __forceinline__ void gstf2(float* p, float2 f){
  union { float2 f; unsigned long long u; } cv; cv.f = f;
  __hip_atomic_store((unsigned long long*)p, cv.u,
                     __ATOMIC_RELAXED, __HIP_MEMORY_SCOPE_AGENT);
}

// per-producer slots, 128B apart (32 u32); quiet per-lane s_sleep poll
__device__ __forceinline__ void wait_slots(const uint32_t* slots, int n, uint32_t tgt, int tid){
  if (tid < n){
    const uint32_t* p = slots + (size_t)tid*32;
    int it = 0;
    while (__hip_atomic_load(p, __ATOMIC_RELAXED, __HIP_MEMORY_SCOPE_AGENT) < tgt){
      __builtin_amdgcn_s_sleep(1);
      if (++it > (1<<22)) break;
    }
  }
  __syncthreads();
}
// concurrent wait on two slot arrays (lanes 0..n0-1 and 32..32+n1-1)
__device__ __forceinline__ void wait_slots2(const uint32_t* s0, int n0,
                                            const uint32_t* s1, int n1,
                                            uint32_t tgt, int tid){
  const uint32_t* p = nullptr;
  if (tid < n0) p = s0 + (size_t)tid*32;
  else if (tid >= 32 && tid < 32 + n1) p = s1 + (size_t)(tid-32)*32;
  if (p){
    int it = 0;
    while (__hip_atomic_load(p, __ATOMIC_RELAXED, __HIP_MEMORY_SCOPE_AGENT) < tgt){
      __builtin_amdgcn_s_sleep(1);
      if (++it > (1<<22)) break;
    }
  }
  __syncthreads();
}
__device__ __forceinline__ void publish_slot(uint32_t* slot, uint32_t v, int tid){
  __syncthreads();
  if (tid == 0)
    __hip_atomic_store(slot, v, __ATOMIC_RELEASE, __HIP_MEMORY_SCOPE_AGENT);
}

__device__ __forceinline__ void fma4(float4& a, const float4& w, float h){
  a.x += w.x*h; a.y += w.y*h; a.z += w.z*h; a.w += w.w*h;
}

// butterfly-sum 8 float4 accumulators over lane bits 3..5
__device__ __forceinline__ void bf8(float4* a){
  #pragma unroll
  for (int d=8; d<64; d<<=1){
    #pragma unroll
    for (int b=0;b<8;++b){
      a[b].x += __shfl_xor(a[b].x, d);
      a[b].y += __shfl_xor(a[b].y, d);
      a[b].z += __shfl_xor(a[b].z, d);
      a[b].w += __shfl_xor(a[b].w, d);
    }
  }
}

// tournament over 256 classes, 4/lane in one 64-lane wave (r8-proven)
__device__ __forceinline__ int sample256(float l0, float l1, float l2, float l3,
                                         const float g[4], int gl){
  float m = fmaxf(fmaxf(l0,l1), fmaxf(l2,l3));
  #pragma unroll
  for (int d=1; d<64; d<<=1) m = fmaxf(m, __shfl_xor(m, d));
  const float e0 = (float)exp((double)(l0-m));
  const float e1 = (float)exp((double)(l1-m));
  const float e2 = (float)exp((double)(l2-m));
  const float e3 = (float)exp((double)(l3-m));
  float ss = ((e0+e1)+(e2+e3));
  #pragma unroll
  for (int d=1; d<64; d<<=1) ss += __shfl_xor(ss, d);
  const float v0 = e0/ss + g[0], v1 = e1/ss + g[1];
  const float v2 = e2/ss + g[2], v3 = e3/ss + g[3];
  float v = v0; int bi = 4*gl;
  if (v1 > v){ v = v1; bi = 4*gl+1; }
  float vB = v2; int biB = 4*gl+2;
  if (v3 > vB){ vB = v3; biB = 4*gl+3; }
  if (vB > v || (vB == v && biB < bi)){ v = vB; bi = biB; }
  #pragma unroll
  for (int d=1; d<64; d<<=1){
    const float ov = __shfl_xor(v, d);
    const int   oi = __shfl_xor(bi, d);
    if (ov > v || (ov == v && oi < bi)){ v = ov; bi = oi; }
  }
  return bi;
}

// ---------------- K0: per-step keys ----------------
__global__ __launch_bounds__(256) void k_keys(uint32_t* __restrict__ kc, uint32_t* __restrict__ kf){
  int t = blockIdx.x*256 + threadIdx.x;
  if (t >= TT) return;
  uint32_t ka, kb;
  threefry(0u, 42u, 0u, (uint32_t)t, &ka, &kb);
  uint32_t c0,c1,f0,f1;
  threefry(ka, kb, 0u, 0u, &c0, &c1);
  threefry(ka, kb, 0u, 1u, &f0, &f1);
  kc[2*t] = c0; kc[2*t+1] = c1;
  kf[2*t] = f0; kf[2*t+1] = f1;
}

// ws offsets (r8 layout)
#define O_SH1   0
#define O_SH1HI 1024
#define O_SFV   2048
#define O_SG    3072
#define O_SYC   6656
#define O_SYF   10240
#define O_KC    13824
#define O_KF    17920
#define O_NCV   22016
#define O_FVS   22080
#define O_NCI   22144
#define O_PRE   22272
#define O_IHB   108288
#define O_HGL   136960
#define O_H0C   194304
#define O_PLC   208640
#define O_PLF   438016
#define WS_ZERO 667392

// ---------------- persistent kernel ----------------
__global__ __launch_bounds__(NTH, 2) void wavernn_persist(
    const float* __restrict__ mels, const float* __restrict__ Wk,
    const float* __restrict__ Wr,  const float* __restrict__ bias,
    const float* __restrict__ W1c, const float* __restrict__ b1c,
    const float* __restrict__ W2c, const float* __restrict__ b2c,
    const float* __restrict__ W1f, const float* __restrict__ b1f,
    const float* __restrict__ W2f, const float* __restrict__ b2f,
    float* __restrict__ out, char* __restrict__ ws)
{
  uint32_t* SH1   = (uint32_t*)(ws + O_SH1);
  uint32_t* SH1HI = (uint32_t*)(ws + O_SH1HI);
  uint32_t* SFV   = (uint32_t*)(ws + O_SFV);
  uint32_t* SG    = (uint32_t*)(ws + O_SG);
  uint32_t* SYC   = (uint32_t*)(ws + O_SYC);
  uint32_t* SYF   = (uint32_t*)(ws + O_SYF);
  const uint32_t* kc = (const uint32_t*)(ws + O_KC);
  const uint32_t* kf = (const uint32_t*)(ws + O_KF);
  float* ncvB = (float*)(ws + O_NCV);   // [2][8]
  float* fvsB = (float*)(ws + O_FVS);   // [2][8]
  int*   nci  = (int*)  (ws + O_NCI);
  float* pre  = (float*)(ws + O_PRE);   // [8][2688]
  float* ihb  = (float*)(ws + O_IHB);   // [8][896]
  float* hgl  = (float*)(ws + O_HGL);   // [2][8*896]
  float* h0c  = (float*)(ws + O_H0C);   // [8][448]
  float* plgtC= (float*)(ws + O_PLC);   // [28][8][256]
  float* plgtF= (float*)(ws + O_PLF);   // [28][8][256]

  __shared__ __align__(16) char smem[46080];
  const int bk = blockIdx.x, tid = threadIdx.x;

  if (bk < 28){
    // ================= GEMM + coarse-gates epilogue =================
    const int ks = tid >> 3, k0 = ks*14;
    const int lane = tid & 63, wv = tid >> 6;
    const int U0 = bk*32;
    const int cb0 = U0 + (tid & 7)*4;
    float* hlf   = (float*)smem;                 // [8][1024] = 32KB
    float* wredf = (float*)(smem + 32768);       // 9216B
    float* gbuf  = (float*)(smem + 41984);       // 4KB
    const int xk = 896 + ks*2;
    const int r0 = ((xk   < 978) ? xk   : 978) - 896;
    const int r1 = ((xk+1 < 978) ? xk+1 : 978) - 896;

    for (int t=0; t<TT; ++t){
      wait_slots(SH1, 8, (uint32_t)t, tid);
      // batched h-stage: 7 independent f2 loads, then LDS writes
      {
        float2 hv[7];
        #pragma unroll
        for (int q=0;q<7;++q) hv[q] = gldf2(hgl + (t&1)*7168 + ((tid + q*NTH)/448)*896 + ((tid + q*NTH) - ((tid + q*NTH)/448)*448)*2);
        #pragma unroll
        for (int q=0;q<7;++q){
          const int i = tid + q*NTH, b = i/448, kp = (i - b*448)*2;
          hlf[b*1024 + kp] = hv[q].x; hlf[b*1024 + kp + 1] = hv[q].y;
        }
      }
      // x region (mel(t), ncv(t-1), pad)
      #pragma unroll
      for (int q=0;q<2;++q){
        const int i = tid + q*NTH, b = i>>7, k2 = i&127;
        float v = 0.f;
        if (k2 < 80) v = mels[((size_t)b*TT + t)*MM + k2];
        else if (k2 == 80) v = gldf(ncvB + ((t+1)&1)*8 + b);
        hlf[b*1024 + 896 + k2] = v;
      }
      __syncthreads();

      for (int g=0; g<3; ++g){
        const int cbg = g*896 + cb0;
        float4 aW[8], aX[8];
        #pragma unroll
        for (int b=0;b<8;++b){ aW[b]=make_float4(0,0,0,0); aX[b]=make_float4(0,0,0,0); }
        #pragma unroll 2
        for (int jj=0;jj<14;++jj){
          const float4 w = *(const float4*)(Wr + (size_t)(k0+jj)*TU + cbg);
          #pragma unroll
          for (int b=0;b<8;++b) fma4(aW[b], w, hlf[b*1024 + k0 + jj]);
        }
        {
          const float4 w0 = *(const float4*)(Wk + (size_t)r0*TU + cbg);
          const float4 w1 = *(const float4*)(Wk + (size_t)r1*TU + cbg);
          #pragma unroll
          for (int b=0;b<8;++b){
            fma4(aX[b], w0, hlf[b*1024 + 896 + ks*2]);
            fma4(aX[b], w1, hlf[b*1024 + 897 + ks*2]);
          }
        }
        if (g < 2){
          #pragma unroll
          for (int b=0;b<8;++b){
            aW[b].x += aX[b].x; aW[b].y += aX[b].y;
            aW[b].z += aX[b].z; aW[b].w += aX[b].w;
          }
          bf8(aW);
          if (lane < 8){
            float* dst = wredf + wv*288 + lane*36;
            #pragma unroll
            for (int b=0;b<8;++b) *(float4*)(dst + b*4) = aW[b];
          }
          __syncthreads();
          if (tid < 128){
            const int rb = tid>>4, rq = tid&15;
            float s0 = 0.f, s1 = 0.f;
            #pragma unroll
            for (int w=0; w<8; ++w){
              const float* wp = wredf + w*288 + (rq>>1)*36 + rb*4 + ((2*rq)&3);
              s0 += wp[0]; s1 += wp[1];
            }
            const int col0 = g*896 + U0 + 2*rq;
            const float v0 = s0 + bias[col0]   + bias[TU + col0];
            const float v1 = s1 + bias[col0+1] + bias[TU + col0+1];
            gstf2(pre + rb*TU + col0, make_float2(v0, v1));
            gbuf[(rb*32 + 2*rq)*4 + g] = v0;
            gbuf[(rb*32 + 2*rq + 1)*4 + g] = v1;
          }
          __syncthreads();
        } else {
          bf8(aW);
          if (lane < 8){
            float* dst = wredf + wv*288 + lane*36;
            #pragma unroll
            for (int b=0;b<8;++b) *(float4*)(dst + b*4) = aW[b];
          }
          __syncthreads();
          if (tid < 128){
            const int rb = tid>>4, rq = tid&15;
            float s0 = 0.f, s1 = 0.f;
            #pragma unroll
            for (int w=0; w<8; ++w){
              const float* wp = wredf + w*288 + (rq>>1)*36 + rb*4 + ((2*rq)&3);
              s0 += wp[0]; s1 += wp[1];
            }
            const int u0 = U0 + 2*rq;
            const float v0 = s0 + bias[TU + 1792 + u0];
            const float v1 = s1 + bias[TU + 1792 + u0 + 1];
            gstf2(ihb + rb*896 + u0, make_float2(v0, v1));
            gbuf[(rb*32 + 2*rq)*4 + 3] = v0;
            gbuf[(rb*32 + 2*rq + 1)*4 + 3] = v1;
          }
          __syncthreads();
          bf8(aX);
          if (lane < 8){
            float* dst = wredf + wv*288 + lane*36;
            #pragma unroll
            for (int b=0;b<8;++b) *(float4*)(dst + b*4) = aX[b];
          }
          __syncthreads();
          if (tid < 128){
            const int rb = tid>>4, rq = tid&15;
            float s0 = 0.f, s1 = 0.f;
            #pragma unroll
            for (int w=0; w<8; ++w){
              const float* wp = wredf + w*288 + (rq>>1)*36 + rb*4 + ((2*rq)&3);
              s0 += wp[0]; s1 += wp[1];
            }
            const int u0 = U0 + 2*rq;
            const float v0 = s0 + bias[1792 + u0];
            const float v1 = s1 + bias[1792 + u0 + 1];
            gstf2(pre + rb*TU + 1792 + u0, make_float2(v0, v1));
            gbuf[(rb*32 + 2*rq)*4 + 2] = v0;
            gbuf[(rb*32 + 2*rq + 1)*4 + 2] = v1;
          }
          __syncthreads();
        }
      }

      if (bk < 14){
        // coarse gates epilogue (needs fv(t-1)), paired
        wait_slots(SFV, 8, (uint32_t)t, tid);
        if (tid < 128){
          const int b = tid>>4, q = tid&15;
          const int u0 = U0 + 2*q;
          const float fv = gldf(fvsB + ((t+1)&1)*8 + b);
          const float2 wz = *(const float2*)(Wk + (size_t)81*TU + u0);
          const float2 wr = *(const float2*)(Wk + (size_t)81*TU + 896 + u0);
          const float2 wx = *(const float2*)(Wk + (size_t)81*TU + 1792 + u0);
          const float* g0 = gbuf + (b*32 + 2*q)*4;
          const float* g1 = g0 + 4;
          const float az0 = g0[0] + fv*wz.x, az1 = g1[0] + fv*wz.y;
          const float ar0 = g0[1] + fv*wr.x, ar1 = g1[1] + fv*wr.y;
          const float ax0 = g0[2] + fv*wx.x, ax1 = g1[2] + fv*wx.y;
          const float z0 = sig_f(az0), z1 = sig_f(az1);
          const float r0g = sig_f(ar0), r1g = sig_f(ar1);
          const float hh0 = tanh_f(ax0 + r0g*g0[3]);
          const float hh1 = tanh_f(ax1 + r1g*g1[3]);
          const float o0 = z0*hlf[b*1024 + u0]     + (1.0f - z0)*hh0;
          const float o1 = z1*hlf[b*1024 + u0 + 1] + (1.0f - z1)*hh1;
          gstf2(h0c + b*HU + u0, make_float2(o0, o1));
        }
      }
      publish_slot(SG + bk*32, (uint32_t)(t+1), tid);
    }
  } else if (bk < 56){
    // ================= head block j: phase C then phase F =================
    const int j = bk - 28;
    float* hstg = (float*)smem;                 // 3584 floats
    float* red1 = (float*)(smem + 14336);       // 512 floats
    float* y1s  = (float*)(smem + 16384);       // 128 floats
    const int outp = tid & 127, ks4 = tid >> 7;
    const int ob = outp >> 4, oc = outp & 15;
    const int i0 = ks4*112;

    for (int t=0; t<TT; ++t){
      // ---------- phase C ----------
      wait_slots(SG, 14, (uint32_t)(t+1), tid);
      {
        float2 hv[4];
        #pragma unroll
        for (int q=0;q<4;++q){
          const int i = tid + q*NTH;
          if (i < 1792) hv[q] = gldf2(h0c + 2*i);
        }
        #pragma unroll
        for (int q=0;q<4;++q){
          const int i = tid + q*NTH;
          if (i < 1792){ hstg[2*i] = hv[q].x; hstg[2*i+1] = hv[q].y; }
        }
      }
      __syncthreads();
      {
        float s = 0.f;
        const float* hb = hstg + ob*HU;
        const float* wb = W1c + (size_t)i0*HU + j*16 + oc;
        #pragma unroll 4
        for (int i=0;i<112;++i) s += hb[i0+i]*wb[(size_t)i*HU];
        red1[outp*4 + ks4] = s;
      }
      __syncthreads();
      if (tid < 128){
        const float v = (red1[tid*4+0]+red1[tid*4+1])+(red1[tid*4+2]+red1[tid*4+3]);
        y1s[tid] = fmaxf(v + b1c[j*16 + (tid&15)], 0.0f);
      }
      __syncthreads();
      #pragma unroll
      for (int p=0;p<2;++p){
        const int po = p*512 + tid;
        const int b = po>>7, cc0 = (po&127)*2;
        float sa = 0.f, sb = 0.f;
        #pragma unroll
        for (int i=0;i<16;++i){
          const float yv = y1s[b*16+i];
          const float2 w2 = *(const float2*)(W2c + (size_t)(j*16+i)*CC + cc0);
          sa += yv*w2.x; sb += yv*w2.y;
        }
        gstf2(plgtC + j*2048 + b*256 + cc0, make_float2(sa, sb));
      }
      publish_slot(SYC + j*32, (uint32_t)(t+1), tid);

      // ---------- phase F ----------
      wait_slots(SH1HI, 8, (uint32_t)(t+1), tid);
      const int hsN = ((t+1)&1)*7168;
      {
        float2 hv[4];
        #pragma unroll
        for (int q=0;q<4;++q){
          const int i = tid + q*NTH;
          if (i < 1792){
            const int b = i/224, ii0 = (i - b*224)*2;
            hv[q] = gldf2(hgl + hsN + b*896 + 448 + ii0);
          }
        }
        #pragma unroll
        for (int q=0;q<4;++q){
          const int i = tid + q*NTH;
          if (i < 1792){
            const int b = i/224, ii0 = (i - b*224)*2;
            hstg[b*448 + ii0] = hv[q].x; hstg[b*448 + ii0 + 1] = hv[q].y;
          }
        }
      }
      __syncthreads();
      {
        float s = 0.f;
        const float* hb = hstg + ob*HU;
        const float* wb = W1f + (size_t)i0*HU + j*16 + oc;
        #pragma unroll 4
        for (int i=0;i<112;++i) s += hb[i0+i]*wb[(size_t)i*HU];
        red1[outp*4 + ks4] = s;
      }
      __syncthreads();
      if (tid < 128){
        const float v = (red1[tid*4+0]+red1[tid*4+1])+(red1[tid*4+2]+red1[tid*4+3]);
        y1s[tid] = fmaxf(v + b1f[j*16 + (tid&15)], 0.0f);
      }
      __syncthreads();
      #pragma unroll
      for (int p=0;p<2;++p){
        const int po = p*512 + tid;
        const int b = po>>7, cc0 = (po&127)*2;
        float sa = 0.f, sb = 0.f;
        #pragma unroll
        for (int i=0;i<16;++i){
          const float yv = y1s[b*16+i];
          const float2 w2 = *(const float2*)(W2f + (size_t)(j*16+i)*CC + cc0);
          sa += yv*w2.x; sb += yv*w2.y;
        }
        gstf2(plgtF + j*2048 + b*256 + cc0, make_float2(sa, sb));
      }
      publish_slot(SYF + j*32, (uint32_t)(t+1), tid);
    }
  } else if (bk < 64){
    // ================= sample_c + fine gates (b = bk-56) =================
    const int b = bk - 56;
    __shared__ int ncSh;
    for (int t=0; t<TT; ++t){
      float gc[4];
      if (tid < 64){
        const uint32_t ka = kc[2*t], kb2 = kc[2*t+1];
        #pragma unroll
        for (int i=0;i<4;++i)
          gc[i] = gumbel_from(ka, kb2, (uint32_t)(b*CC + 4*tid + i));
      }
      wait_slots2(SYC, 28, SG, 28, (uint32_t)(t+1), tid);
      if (tid < 64){
        float s0=0.f,s1=0.f,s2=0.f,s3=0.f;
        const float* pb = plgtC + b*256 + 4*tid;
        #pragma unroll
        for (int h=0; h<2; ++h){
          float2 pA[14], pB[14];
          #pragma unroll
          for (int q=0;q<14;++q){
            pA[q] = gldf2(pb + (h*14+q)*2048);
            pB[q] = gldf2(pb + (h*14+q)*2048 + 2);
          }
          #pragma unroll
          for (int q=0;q<14;++q){
            s0 += pA[q].x; s1 += pA[q].y; s2 += pB[q].x; s3 += pB[q].y;
          }
        }
        const float l0 = s0 + b2c[4*tid+0], l1 = s1 + b2c[4*tid+1];
        const float l2 = s2 + b2c[4*tid+2], l3 = s3 + b2c[4*tid+3];
        const int nc = sample256(l0,l1,l2,l3, gc, tid);
        if (tid == 0){
          gsti(nci + b, nc);
          gstf(ncvB + (t&1)*8 + b, (float)nc/255.0f*2.0f - 1.0f);
          ncSh = nc;
        }
      }
      __syncthreads();
      const float ncv = (float)ncSh/255.0f*2.0f - 1.0f;
      const float fv = gldf(fvsB + ((t+1)&1)*8 + b);
      const int hsO = (t&1)*7168, hsN = ((t+1)&1)*7168;
      // hi half (paired)
      if (tid < 224){
        const int u0 = 448 + 2*tid;
        const float2 pz = gldf2(pre + b*TU + u0);
        const float2 pr = gldf2(pre + b*TU + 896 + u0);
        const float2 px = gldf2(pre + b*TU + 1792 + u0);
        const float2 ih = gldf2(ihb + b*896 + u0);
        const float2 ho = gldf2(hgl + hsO + b*896 + u0);
        const float2 w81z = *(const float2*)(Wk + (size_t)81*TU + u0);
        const float2 w81r = *(const float2*)(Wk + (size_t)81*TU + 896 + u0);
        const float2 w81x = *(const float2*)(Wk + (size_t)81*TU + 1792 + u0);
        const float2 w82z = *(const float2*)(Wk + (size_t)82*TU + u0);
        const float2 w82r = *(const float2*)(Wk + (size_t)82*TU + 896 + u0);
        const float2 w82x = *(const float2*)(Wk + (size_t)82*TU + 1792 + u0);
        const float az0 = pz.x + fv*w81z.x + ncv*w82z.x;
        const float az1 = pz.y + fv*w81z.y + ncv*w82z.y;
        const float ar0 = pr.x + fv*w81r.x + ncv*w82r.x;
        const float ar1 = pr.y + fv*w81r.y + ncv*w82r.y;
        const float ax0 = px.x + fv*w81x.x + ncv*w82x.x;
        const float ax1 = px.y + fv*w81x.y + ncv*w82x.y;
        const float z0 = sig_f(az0), z1 = sig_f(az1);
        const float r0g = sig_f(ar0), r1g = sig_f(ar1);
        const float h0v = z0*ho.x + (1.0f - z0)*tanh_f(ax0 + r0g*ih.x);
        const float h1v = z1*ho.y + (1.0f - z1)*tanh_f(ax1 + r1g*ih.y);
        gstf2(hgl + hsN + b*896 + u0, make_float2(h0v, h1v));
      }
      publish_slot(SH1HI + b*32, (uint32_t)(t+1), tid);
      // lo half (paired)
      if (tid < 224){
        const int u0 = 2*tid;
        const float2 pz = gldf2(pre + b*TU + u0);
        const float2 pr = gldf2(pre + b*TU + 896 + u0);
        const float2 px = gldf2(pre + b*TU + 1792 + u0);
        const float2 ih = gldf2(ihb + b*896 + u0);
        const float2 ho = gldf2(hgl + hsO + b*896 + u0);
        const float2 w81z = *(const float2*)(Wk + (size_t)81*TU + u0);
        const float2 w81r = *(const float2*)(Wk + (size_t)81*TU + 896 + u0);
        const float2 w81x = *(const float2*)(Wk + (size_t)81*TU + 1792 + u0);
        const float2 w82z = *(const float2*)(Wk + (size_t)82*TU + u0);
        const float2 w82r = *(const float2*)(Wk + (size_t)82*TU + 896 + u0);
        const float2 w82x = *(const float2*)(Wk + (size_t)82*TU + 1792 + u0);
        const float az0 = pz.x + fv*w81z.x + ncv*w82z.x;
        const float az1 = pz.y + fv*w81z.y + ncv*w82z.y;
        const float ar0 = pr.x + fv*w81r.x + ncv*w82r.x;
        const float ar1 = pr.y + fv*w81r.y + ncv*w82r.y;
        const float ax0 = px.x + fv*w81x.x + ncv*w82x.x;
        const float ax1 = px.y + fv*w81x.y + ncv*w82x.y;
        const float z0 = sig_f(az0), z1 = sig_f(az1);
        const float r0g = sig_f(ar0), r1g = sig_f(ar1);
        const float h0v = z0*ho.x + (1.0f - z0)*tanh_f(ax0 + r0g*ih.x);
        const float h1v = z1*ho.y + (1.0f - z1)*tanh_f(ax1 + r1g*ih.y);
        gstf2(hgl + hsN + b*896 + u0, make_float2(h0v, h1v));
      }
      publish_slot(SH1 + b*32, (uint32_t)(t+1), tid);
    }
  } else {
    // ================= sample_f (b = bk-64) =================
    const int b = bk - 64;
    for (int t=0; t<TT; ++t){
      float gf[4];
      if (tid < 64){
        const uint32_t ka = kf[2*t], kb2 = kf[2*t+1];
        #pragma unroll
        for (int i=0;i<4;++i)
          gf[i] = gumbel_from(ka, kb2, (uint32_t)(b*CC + 4*tid + i));
      }
      wait_slots(SYF, 28, (uint32_t)(t+1), tid);
      if (tid < 64){
        float s0=0.f,s1=0.f,s2=0.f,s3=0.f;
        const float* pb = plgtF + b*256 + 4*tid;
        #pragma unroll
        for (int h=0; h<2; ++h){
          float2 pA[14], pB[14];
          #pragma unroll
          for (int q=0;q<14;++q){
            pA[q] = gldf2(pb + (h*14+q)*2048);
            pB[q] = gldf2(pb + (h*14+q)*2048 + 2);
          }
          #pragma unroll
          for (int q=0;q<14;++q){
            s0 += pA[q].x; s1 += pA[q].y; s2 += pB[q].x; s3 += pB[q].y;
          }
        }
        const float l0 = s0 + b2f[4*tid+0], l1 = s1 + b2f[4*tid+1];
        const float l2 = s2 + b2f[4*tid+2], l3 = s3 + b2f[4*tid+3];
        const int nf = sample256(l0,l1,l2,l3, gf, tid);
        if (tid == 0){
          gstf(fvsB + (t&1)*8 + b, (float)nf/255.0f*2.0f - 1.0f);
          const int nc = gldi(nci + b);
          out[(size_t)b*TT + t] = ((float)nc*256.0f + (float)nf)/32767.5f - 1.0f;
        }
      }
      publish_slot(SFV + b*32, (uint32_t)(t+1), tid);
    }
  }
}

extern "C" void kernel_launch(void* const* d_in, const int* in_sizes, int n_in,
                              void* d_out, int out_size, void* d_ws, size_t ws_size,
                              hipStream_t stream) {
  const float* mels = (const float*)d_in[0];
  const float* Wk   = (const float*)d_in[1];
  const float* Wr   = (const float*)d_in[2];
  const float* bias = (const float*)d_in[3];
  const float* W1c  = (const float*)d_in[4];
  const float* b1c  = (const float*)d_in[5];
  const float* W2c  = (const float*)d_in[6];
  const float* b2c  = (const float*)d_in[7];
  const float* W1f  = (const float*)d_in[8];
  const float* b1f  = (const float*)d_in[9];
  const float* W2f  = (const float*)d_in[10];
  const float* b2f  = (const float*)d_in[11];
  float* out = (float*)d_out;
  char* wsb = (char*)d_ws;

  uint32_t* kc = (uint32_t*)(wsb + O_KC);
  uint32_t* kf = (uint32_t*)(wsb + O_KF);

  hipMemsetAsync(d_ws, 0, WS_ZERO, stream);
  k_keys<<<2,256,0,stream>>>(kc, kf);

  void* args[] = { (void*)&mels, (void*)&Wk, (void*)&Wr, (void*)&bias,
                   (void*)&W1c, (void*)&b1c, (void*)&W2c, (void*)&b2c,
                   (void*)&W1f, (void*)&b1f, (void*)&W2f, (void*)&b2f,
                   (void*)&out, (void*)&wsb };
  hipLaunchCooperativeKernel((const void*)wavernn_persist, dim3(NBLK), dim3(NTH),
                             args, 0, stream);
}